// Round 9
// baseline (996.181 us; speedup 1.0000x reference)
//
#include <hip/hip_runtime.h>

#define NN 100000
#define NE 3200000
#define F 256
#define NCLS 40
#define NC 391              // coarse buckets of 256 dst nodes: 391*256 >= NN
#define NBLK_H 256          // histogram/scatter blocks (1 per CU); NE/NBLK_H = 12500
#define EPB (NE / NBLK_H)   // 12500 edges per block slice
#define CW 25000            // cnt_out words (NN/4, byte-packed)

using h4 = __attribute__((ext_vector_type(4))) _Float16;
using h8 = __attribute__((ext_vector_type(8))) _Float16;
using f4 = __attribute__((ext_vector_type(4))) float;

// ---------------- LDS-privatized histogram: out-degree (u8-packed) + coarse dst buckets ----------------
__global__ __launch_bounds__(256) void hist_k(const int* __restrict__ src,
                                              const int* __restrict__ dst,
                                              unsigned* __restrict__ pcnt,
                                              unsigned* __restrict__ pcc) {
    __shared__ unsigned hsrc[CW];     // 100 KB: per-node u8 counts, 4 nodes/word
    __shared__ unsigned hc[NC];       // 1.6 KB coarse bucket counts
    int t = threadIdx.x, b = blockIdx.x;
    for (int i = t; i < CW; i += 256) hsrc[i] = 0;
    for (int i = t; i < NC; i += 256) hc[i] = 0;
    __syncthreads();
    int beg = b * EPB, end = beg + EPB;
    for (int e = beg + t; e < end; e += 256) {
        int s = src[e];
        atomicAdd(&hsrc[s >> 2], 1u << (8 * (s & 3)));
        atomicAdd(&hc[dst[e] >> 8], 1u);
    }
    __syncthreads();
    unsigned* pc = pcnt + (size_t)b * CW;
    for (int i = t; i < CW; i += 256) pc[i] = hsrc[i];
    unsigned* pb = pcc + (size_t)b * NC;
    for (int i = t; i < NC; i += 256) pb[i] = hc[i];
}

// ---------------- reduce partials -> nout (4 nodes per thread) ----------------
__global__ void rednout_k(const unsigned* __restrict__ pcnt, float* __restrict__ nout) {
    int w = blockIdx.x * blockDim.x + threadIdx.x;
    if (w >= CW) return;
    unsigned s0 = 0, s1 = 0, s2 = 0, s3 = 0;
    for (int b = 0; b < NBLK_H; b++) {
        unsigned v = pcnt[(size_t)b * CW + w];
        s0 += v & 255u; s1 += (v >> 8) & 255u; s2 += (v >> 16) & 255u; s3 += v >> 24;
    }
    float4 o;
    o.x = rsqrtf(fmaxf((float)s0, 1.f));
    o.y = rsqrtf(fmaxf((float)s1, 1.f));
    o.z = rsqrtf(fmaxf((float)s2, 1.f));
    o.w = rsqrtf(fmaxf((float)s3, 1.f));
    *(float4*)(nout + w * 4) = o;
}

// ---------------- per-bucket scan over blocks ----------------
__global__ __launch_bounds__(256) void offsets_k(const unsigned* __restrict__ pcc,
                                                 unsigned* __restrict__ curoff,
                                                 unsigned* __restrict__ totals) {
    __shared__ unsigned sh[256];
    int c = blockIdx.x, t = threadIdx.x;
    unsigned v = pcc[(size_t)t * NC + c];
    sh[t] = v;
    __syncthreads();
    for (int off = 1; off < 256; off <<= 1) {
        unsigned x = (t >= off) ? sh[t - off] : 0;
        __syncthreads();
        sh[t] += x;
        __syncthreads();
    }
    curoff[(size_t)t * NC + c] = sh[t] - v;
    if (t == 255) totals[c] = sh[255];
}

// ---------------- exclusive scan of coarse totals -> cbase[NC+1] ----------------
__global__ __launch_bounds__(512) void base_k(const unsigned* __restrict__ totals,
                                              int* __restrict__ cbase) {
    __shared__ unsigned sh[512];
    int t = threadIdx.x;
    unsigned v = (t < NC) ? totals[t] : 0;
    sh[t] = v;
    __syncthreads();
    for (int off = 1; off < 512; off <<= 1) {
        unsigned x = (t >= off) ? sh[t - off] : 0;
        __syncthreads();
        sh[t] += x;
        __syncthreads();
    }
    if (t < NC) cbase[t] = (int)(sh[t] - v);
    if (t == 0) cbase[NC] = NE;
}

// ---------------- pass 1: scatter edges into coarse regions, LDS cursors ----------------
__global__ __launch_bounds__(256) void p1scat_k(const int* __restrict__ src,
                                                const int* __restrict__ dst,
                                                const int* __restrict__ cbase,
                                                const unsigned* __restrict__ curoff,
                                                unsigned* __restrict__ ebuf) {
    __shared__ int cur[NC];
    int t = threadIdx.x, b = blockIdx.x;
    for (int i = t; i < NC; i += 256)
        cur[i] = cbase[i] + (int)curoff[(size_t)b * NC + i];
    __syncthreads();
    int beg = b * EPB, end = beg + EPB;
    for (int e = beg + t; e < end; e += 256) {
        int d = dst[e];
        int p = atomicAdd(&cur[d >> 8], 1);
        ebuf[p] = (unsigned)src[e] | ((unsigned)(d & 255) << 17);
    }
}

// ---------------- pass 2: per-coarse-bucket fine sort -> csr_src, row_ptr, nin ----------------
__global__ __launch_bounds__(256) void p2build_k(const int* __restrict__ cbase,
                                                 const unsigned* __restrict__ ebuf,
                                                 int* __restrict__ csr_src,
                                                 int* __restrict__ row_ptr,
                                                 float* __restrict__ nin) {
    __shared__ int cnt[256], cur[256], sh[256];
    int c = blockIdx.x, t = threadIdx.x;
    int beg = cbase[c], end = cbase[c + 1];
    cnt[t] = 0;
    __syncthreads();
    for (int e = beg + t; e < end; e += 256)
        atomicAdd(&cnt[(ebuf[e] >> 17) & 255], 1);
    __syncthreads();
    int v = cnt[t];
    sh[t] = v;
    __syncthreads();
    for (int off = 1; off < 256; off <<= 1) {
        int x = (t >= off) ? sh[t - off] : 0;
        __syncthreads();
        sh[t] += x;
        __syncthreads();
    }
    int pref = sh[t] - v;
    int node = c * 256 + t;
    if (node <= NN) row_ptr[node] = beg + pref;
    if (node < NN)  nin[node] = rsqrtf(fmaxf((float)v, 1.f));
    cur[t] = pref;
    __syncthreads();
    for (int e = beg + t; e < end; e += 256) {
        unsigned w = ebuf[e];
        int p = atomicAdd(&cur[(w >> 17) & 255], 1);
        csr_src[beg + p] = (int)(w & 0x1FFFFu);
    }
}

// ---------------- features fp32 -> fp16, scaled by nout[row] ----------------
__global__ void convfeat_k(const float4* __restrict__ fin, const float* __restrict__ nout,
                           h4* __restrict__ fout, int n4) {
    int i = blockIdx.x * blockDim.x + threadIdx.x;
    if (i < n4) {
        float s = nout[i >> 6];
        float4 v = fin[i];
        h4 o;
        o[0] = (_Float16)(v.x * s);
        o[1] = (_Float16)(v.y * s);
        o[2] = (_Float16)(v.z * s);
        o[3] = (_Float16)(v.w * s);
        fout[i] = o;
    }
}

// ---------------- W [K=256][ncin] -> Wt fp16 [npad][256], zero-pad cols ----------------
__global__ void convw_k(const float* __restrict__ W, _Float16* __restrict__ Wt,
                        int ncin, int npad) {
    int i = blockIdx.x * blockDim.x + threadIdx.x;
    if (i < npad * 256) {
        int n = i >> 8, k = i & 255;
        Wt[i] = (n < ncin) ? (_Float16)W[k * ncin + n] : (_Float16)0.0f;
    }
}

// ---------------- CSR aggregation, 256-wide (layer 0 control) ----------------
__global__ __launch_bounds__(256) void agg256h_k(
        const int* __restrict__ row_ptr, const int* __restrict__ csr_src,
        const _Float16* __restrict__ h, _Float16* __restrict__ agg, int nN) {
    int node = (blockIdx.x * blockDim.x + threadIdx.x) >> 6;
    int lane = threadIdx.x & 63;
    if (node >= nN) return;
    int half = lane >> 5, col = lane & 31;
    int beg = row_ptr[node], end = row_ptr[node + 1];
    f4 a[4][2];
#pragma unroll
    for (int u = 0; u < 4; u++) { a[u][0] = (f4){0,0,0,0}; a[u][1] = (f4){0,0,0,0}; }
    int e = beg;
    for (; e + 7 < end; e += 8) {
        int s[4];
#pragma unroll
        for (int u = 0; u < 4; u++) s[u] = csr_src[e + 2 * u + half];
        h8 v[4];
#pragma unroll
        for (int u = 0; u < 4; u++)
            v[u] = *(const h8*)(h + (size_t)s[u] * F + col * 8);
#pragma unroll
        for (int u = 0; u < 4; u++)
#pragma unroll
            for (int j = 0; j < 8; j++) a[u][j >> 2][j & 3] += (float)v[u][j];
    }
    for (int t = e + half; t < end; t += 2) {
        h8 v = *(const h8*)(h + (size_t)csr_src[t] * F + col * 8);
#pragma unroll
        for (int j = 0; j < 8; j++) a[0][j >> 2][j & 3] += (float)v[j];
    }
    float r[8];
#pragma unroll
    for (int j = 0; j < 8; j++)
        r[j] = (a[0][j >> 2][j & 3] + a[1][j >> 2][j & 3])
             + (a[2][j >> 2][j & 3] + a[3][j >> 2][j & 3]);
#pragma unroll
    for (int j = 0; j < 8; j++) r[j] += __shfl_xor(r[j], 32);
    if (half == 0) {
        h8 o;
#pragma unroll
        for (int j = 0; j < 8; j++) o[j] = (_Float16)r[j];
        *(h8*)(agg + (size_t)node * F + col * 8) = o;
    }
}

// ---------------- CSR aggregation, 64-wide + final epilogue ----------------
__global__ __launch_bounds__(256) void agg64h_k(
        const int* __restrict__ row_ptr, const int* __restrict__ csr_src,
        const _Float16* __restrict__ t3, const float* __restrict__ nin,
        const float* __restrict__ b2, float* __restrict__ out, int nN) {
    int node = (blockIdx.x * blockDim.x + threadIdx.x) >> 6;
    int lane = threadIdx.x & 63;
    if (node >= nN) return;
    int q = lane >> 4, c = lane & 15;
    int beg = row_ptr[node], end = row_ptr[node + 1];
    f4 a0 = {0,0,0,0}, a1 = {0,0,0,0};
    int e = beg;
    for (; e + 7 < end; e += 8) {
        int s0 = csr_src[e + q], s1 = csr_src[e + 4 + q];
        h4 v0 = *(const h4*)(t3 + (size_t)s0 * 64 + c * 4);
        h4 v1 = *(const h4*)(t3 + (size_t)s1 * 64 + c * 4);
#pragma unroll
        for (int j = 0; j < 4; j++) { a0[j] += (float)v0[j]; a1[j] += (float)v1[j]; }
    }
    for (int t = e + q; t < end; t += 4) {
        h4 v = *(const h4*)(t3 + (size_t)csr_src[t] * 64 + c * 4);
#pragma unroll
        for (int j = 0; j < 4; j++) a0[j] += (float)v[j];
    }
    float r[4];
#pragma unroll
    for (int j = 0; j < 4; j++) {
        r[j] = a0[j] + a1[j];
        r[j] += __shfl_xor(r[j], 16);
        r[j] += __shfl_xor(r[j], 32);
    }
    if (lane < 10) {
        float ni = nin[node];
        float4 o;
        o.x = r[0] * ni + b2[lane * 4 + 0];
        o.y = r[1] * ni + b2[lane * 4 + 1];
        o.z = r[2] * ni + b2[lane * 4 + 2];
        o.w = r[3] * ni + b2[lane * 4 + 3];
        *(float4*)(out + (size_t)node * NCLS + lane * 4) = o;
    }
}

// ---------------- LDS-resident f16 MFMA GEMM (layer 0 control) ----------------
template <int NT, int EPI>
__global__ __launch_bounds__(512) void gemm_lds_k(
        const _Float16* __restrict__ A, const _Float16* __restrict__ Wt,
        _Float16* __restrict__ C, int M,
        const float* __restrict__ nin, const float* __restrict__ nout,
        const float* __restrict__ bias) {
    constexpr int COLS = NT * 16;
    __shared__ _Float16 lds[COLS * 256];
    char* ldsb = (char*)lds;

    const int tid  = threadIdx.x;
    const int lane = tid & 63;
    const int w    = tid >> 6;
    const int row0 = blockIdx.x * 128;

#pragma unroll
    for (int i = 0; i < COLS / 16; i++) {
        int idx  = (i * 512 + tid) * 8;
        int byte = idx * 2;
        int row  = byte >> 9;
        int swz  = byte ^ ((row & 7) << 4);
        h8 v = *(const h8*)(Wt + idx);
        *(h8*)(ldsb + swz) = v;
    }

    int arow = row0 + w * 16 + (lane & 15);
    if (arow >= M) arow = M - 1;
    const _Float16* Ap = A + (size_t)arow * 256 + (lane >> 4) * 8;
    h8 areg[8];
#pragma unroll
    for (int i = 0; i < 8; i++) areg[i] = *(const h8*)(Ap + i * 32);

    __syncthreads();

    f4 acc[NT];
#pragma unroll
    for (int n = 0; n < NT; n++) acc[n] = (f4){0.f, 0.f, 0.f, 0.f};

#pragma unroll
    for (int k0 = 0; k0 < 8; k0++) {
        int kb = (k0 * 32 + (lane >> 4) * 8) * 2;
#pragma unroll
        for (int n = 0; n < NT; n++) {
            int r    = n * 16 + (lane & 15);
            int byte = r * 512 + kb;
            int swz  = byte ^ ((r & 7) << 4);
            h8 bf = *(const h8*)(ldsb + swz);
            acc[n] = __builtin_amdgcn_mfma_f32_16x16x32_f16(areg[k0], bf, acc[n], 0, 0, 0);
        }
    }

    __syncthreads();

    const int g  = lane >> 4;
    const int rb = row0 + w * 16 + g * 4;
    float si[4], so[4];
    if (EPI) {
#pragma unroll
        for (int r = 0; r < 4; r++) {
            int rr = rb + r; if (rr >= M) rr = M - 1;
            si[r] = nin[rr];
            so[r] = nout[rr];
        }
    }
    char* warea = ldsb + w * (16 * COLS * 2);
#pragma unroll
    for (int n = 0; n < NT; n++) {
        float bb = EPI ? bias[n * 16 + (lane & 15)] : 0.f;
#pragma unroll
        for (int r = 0; r < 4; r++) {
            float x = acc[n][r];
            if (EPI) x = fmaxf(x * si[r] + bb, 0.f) * so[r];
            int lrow = g * 4 + r;
            int lcol = n * 16 + (lane & 15);
            *(_Float16*)(warea + (size_t)(lrow * COLS + lcol) * 2) = (_Float16)x;
        }
    }

    _Float16* Crow = C + (size_t)(row0 + w * 16) * COLS;
#pragma unroll
    for (int i = 0; i < COLS / 32; i++) {
        int off  = i * 1024 + lane * 16;
        int lrow = off / (COLS * 2);
        int grow = row0 + w * 16 + lrow;
        h8 v = *(const h8*)(warea + off);
        if (grow < M) *(h8*)((char*)Crow + off) = v;
    }
}

// ---------------- FUSED layers 1+2: gather -> @W1 epilogue -> @W2 -> t3 ----------------
// Per 128-node block: gather into swizzled LDS h-tile (agg256h inner loop),
// h1 = relu(agg@W1*nin+b)*nout via two 64KB Wt-half passes (stash in regs),
// rebuild h1 in LDS, t3 = h1@W2 (64 cols), write ONLY t3 (h1 never hits HBM).
__global__ __launch_bounds__(512) void fused12_k(
        const int* __restrict__ row_ptr, const int* __restrict__ csr_src,
        const _Float16* __restrict__ hsrc,
        const _Float16* __restrict__ Wt1, const _Float16* __restrict__ Wt2,
        _Float16* __restrict__ t3, const float* __restrict__ nin,
        const float* __restrict__ nout, const float* __restrict__ bias) {
    __shared__ _Float16 htile[128 * 256];   // 64KB: gather tile (swz) -> later Wt2 (swz) + t3 tile
    __shared__ _Float16 wbuf[128 * 256];    // 64KB: Wt1 half (swz) -> h1 tile (swz)
    char* hb = (char*)htile;
    char* wb = (char*)wbuf;

    const int tid  = threadIdx.x;
    const int lane = tid & 63;
    const int w    = tid >> 6;
    const int row0 = blockIdx.x * 128;
    const int half = lane >> 5, col = lane & 31;
    const int g    = lane >> 4;

    // ---- phase 1: gather 16 nodes per wave into htile (8 rows in flight/wave) ----
    for (int n = 0; n < 16; n++) {
        int node = row0 + w * 16 + n;
        f4 a[4][2];
#pragma unroll
        for (int u = 0; u < 4; u++) { a[u][0] = (f4){0,0,0,0}; a[u][1] = (f4){0,0,0,0}; }
        if (node < NN) {
            int beg = row_ptr[node], end = row_ptr[node + 1];
            int e = beg;
            for (; e + 7 < end; e += 8) {
                int s[4];
#pragma unroll
                for (int u = 0; u < 4; u++) s[u] = csr_src[e + 2 * u + half];
                h8 v[4];
#pragma unroll
                for (int u = 0; u < 4; u++)
                    v[u] = *(const h8*)(hsrc + (size_t)s[u] * F + col * 8);
#pragma unroll
                for (int u = 0; u < 4; u++)
#pragma unroll
                    for (int j = 0; j < 8; j++) a[u][j >> 2][j & 3] += (float)v[u][j];
            }
            for (int t = e + half; t < end; t += 2) {
                h8 v = *(const h8*)(hsrc + (size_t)csr_src[t] * F + col * 8);
#pragma unroll
                for (int j = 0; j < 8; j++) a[0][j >> 2][j & 3] += (float)v[j];
            }
        }
        float r[8];
#pragma unroll
        for (int j = 0; j < 8; j++)
            r[j] = (a[0][j >> 2][j & 3] + a[1][j >> 2][j & 3])
                 + (a[2][j >> 2][j & 3] + a[3][j >> 2][j & 3]);
#pragma unroll
        for (int j = 0; j < 8; j++) r[j] += __shfl_xor(r[j], 32);
        if (half == 0) {
            h8 o;
#pragma unroll
            for (int j = 0; j < 8; j++) o[j] = (_Float16)r[j];
            int lr = w * 16 + n;
            int byte = lr * 512 + col * 16;
            *(h8*)(hb + (byte ^ ((lr & 7) << 4))) = o;
        }
    }

    // ---- A-fragments from htile (wave-local rows; no barrier needed) ----
    h8 areg[8];
    {
        int lr = w * 16 + (lane & 15);
#pragma unroll
        for (int k0 = 0; k0 < 8; k0++) {
            int byte = lr * 512 + k0 * 64 + (lane >> 4) * 16;
            areg[k0] = *(const h8*)(hb + (byte ^ ((lr & 7) << 4)));
        }
    }

    float si[4], so[4];
#pragma unroll
    for (int r = 0; r < 4; r++) {
        int rr = row0 + w * 16 + g * 4 + r; if (rr >= NN) rr = NN - 1;
        si[r] = nin[rr]; so[r] = nout[rr];
    }

    h4 stash[2][8];
#pragma unroll
    for (int p = 0; p < 2; p++) {
        if (p == 1) __syncthreads();          // all waves done reading Wt half A
        // stage Wt1 half p (64KB), swizzled
#pragma unroll
        for (int i = 0; i < 8; i++) {
            int idx = (i * 512 + tid) * 8;
            int byte = idx * 2;
            int row = byte >> 9;
            *(h8*)(wb + (byte ^ ((row & 7) << 4))) =
                *(const h8*)(Wt1 + (size_t)p * 128 * 256 + idx);
        }
        __syncthreads();
        f4 acc[8];
#pragma unroll
        for (int n = 0; n < 8; n++) acc[n] = (f4){0,0,0,0};
#pragma unroll
        for (int k0 = 0; k0 < 8; k0++) {
            int kb = k0 * 64 + (lane >> 4) * 16;
#pragma unroll
            for (int n = 0; n < 8; n++) {
                int rr = n * 16 + (lane & 15);
                int byte = rr * 512 + kb;
                h8 bf = *(const h8*)(wb + (byte ^ ((rr & 7) << 4)));
                acc[n] = __builtin_amdgcn_mfma_f32_16x16x32_f16(areg[k0], bf, acc[n], 0, 0, 0);
            }
        }
#pragma unroll
        for (int n = 0; n < 8; n++) {
            float bb = bias[p * 128 + n * 16 + (lane & 15)];
#pragma unroll
            for (int r = 0; r < 4; r++)
                stash[p][n][r] = (_Float16)(fmaxf(acc[n][r] * si[r] + bb, 0.f) * so[r]);
        }
    }
    __syncthreads();   // done reading wbuf pass B; htile long dead

    // ---- rebuild h1 tile in wbuf (swizzled, wave-local rows); stage Wt2 into htile ----
#pragma unroll
    for (int p = 0; p < 2; p++)
#pragma unroll
        for (int n = 0; n < 8; n++)
#pragma unroll
            for (int r = 0; r < 4; r++) {
                int lr = w * 16 + g * 4 + r;
                int c = p * 128 + n * 16 + (lane & 15);
                int byte = lr * 512 + c * 2;
                *(_Float16*)(wb + (byte ^ ((lr & 7) << 4))) = stash[p][n][r];
            }
#pragma unroll
    for (int i = 0; i < 4; i++) {          // Wt2 [64][256] = 32KB, swizzled
        int idx = (i * 512 + tid) * 8;
        int byte = idx * 2;
        int row = byte >> 9;
        *(h8*)(hb + (byte ^ ((row & 7) << 4))) = *(const h8*)(Wt2 + idx);
    }
    __syncthreads();

    // ---- t3 = h1 @ Wt2^T (64 cols) ----
    h8 areg2[8];
    {
        int lr = w * 16 + (lane & 15);
#pragma unroll
        for (int k0 = 0; k0 < 8; k0++) {
            int byte = lr * 512 + k0 * 64 + (lane >> 4) * 16;
            areg2[k0] = *(const h8*)(wb + (byte ^ ((lr & 7) << 4)));
        }
    }
    f4 acc2[4];
#pragma unroll
    for (int n = 0; n < 4; n++) acc2[n] = (f4){0,0,0,0};
#pragma unroll
    for (int k0 = 0; k0 < 8; k0++) {
        int kb = k0 * 64 + (lane >> 4) * 16;
#pragma unroll
        for (int n = 0; n < 4; n++) {
            int rr = n * 16 + (lane & 15);
            int byte = rr * 512 + kb;
            h8 bf = *(const h8*)(hb + (byte ^ ((rr & 7) << 4)));
            acc2[n] = __builtin_amdgcn_mfma_f32_16x16x32_f16(areg2[k0], bf, acc2[n], 0, 0, 0);
        }
    }
    // t3 tile [128][64] fp16 = 16KB at htile+32KB, swizzled within 128B rows
    char* tb = hb + 32768;
#pragma unroll
    for (int n = 0; n < 4; n++)
#pragma unroll
        for (int r = 0; r < 4; r++) {
            int lr = w * 16 + g * 4 + r;
            int c = n * 16 + (lane & 15);
            int byte = lr * 128 + c * 2;
            *(_Float16*)(tb + (byte ^ ((lr & 7) << 4))) = (_Float16)acc2[n][r];
        }
    __syncthreads();
    // coalesced 16B stores of the 16KB tile
#pragma unroll
    for (int i = 0; i < 2; i++) {
        int off = i * 8192 + tid * 16;
        int lr = off >> 7;
        h8 v = *(const h8*)(tb + (off ^ ((lr & 7) << 4)));
        int grow = row0 + lr;
        if (grow < NN)
            *(h8*)((char*)t3 + (size_t)grow * 128 + (off & 127)) = v;
    }
}

extern "C" void kernel_launch(void* const* d_in, const int* in_sizes, int n_in,
                              void* d_out, int out_size, void* d_ws, size_t ws_size,
                              hipStream_t stream) {
    const float* features = (const float*)d_in[0];
    const int*   src      = (const int*)d_in[1];
    const int*   dst      = (const int*)d_in[2];
    const float* W0       = (const float*)d_in[3];
    const float* b0       = (const float*)d_in[4];
    const float* W1       = (const float*)d_in[5];
    const float* b1       = (const float*)d_in[6];
    const float* W2       = (const float*)d_in[7];
    const float* b2       = (const float*)d_in[8];
    float* out = (float*)d_out;

    // ---- workspace carve (16B-aligned sections) ----
    char* ws = (char*)d_ws;
    const size_t H_BYTES = (size_t)NN * F * 2;             // 51.2 MB
    _Float16* hA   = (_Float16*)(ws);
    _Float16* hB   = (_Float16*)(ws + H_BYTES);
    _Float16* t3h  = (_Float16*)(ws + 2 * H_BYTES);        // [NN,64] fp16
    char* q = ws + 2 * H_BYTES + (size_t)NN * 64 * 2;
    int* csr_src    = (int*)q;               q += (size_t)NE * 4;             // 12.8 MB
    unsigned* ebuf  = (unsigned*)q;          q += (size_t)NE * 4;             // 12.8 MB
    unsigned* pcnt  = (unsigned*)q;          q += (size_t)NBLK_H * CW * 4;    // 25.6 MB
    unsigned* pcc   = (unsigned*)q;          q += (size_t)NBLK_H * NC * 4 + 1024;
    unsigned* curoff= (unsigned*)q;          q += (size_t)NBLK_H * NC * 4 + 1024;
    char* p = q;
    const size_t SB = 401408;
    unsigned* totals = (unsigned*)(p + 0 * SB);
    int*   cbase   = (int*)(p + 1 * SB);
    int*   row_ptr = (int*)(p + 2 * SB);
    float* nout    = (float*)(p + 3 * SB);
    float* nin     = (float*)(p + 4 * SB);
    _Float16* Wt0  = (_Float16*)(p + 5 * SB);              // 128 KB
    _Float16* Wt1  = (_Float16*)(p + 5 * SB + 131072);
    _Float16* Wt2  = (_Float16*)(p + 5 * SB + 262144);     // 32 KB

    const int AGG_BLOCKS = (NN * 64 + 255) / 256;
    const int GB = (NN + 127) / 128;                       // 782 blocks

    // ---- CSR build: LDS histograms -> offset scans -> 2-pass radix ----
    hist_k<<<NBLK_H, 256, 0, stream>>>(src, dst, pcnt, pcc);
    rednout_k<<<(CW + 255) / 256, 256, 0, stream>>>(pcnt, nout);
    offsets_k<<<NC, 256, 0, stream>>>(pcc, curoff, totals);
    base_k<<<1, 512, 0, stream>>>(totals, cbase);
    p1scat_k<<<NBLK_H, 256, 0, stream>>>(src, dst, cbase, curoff, ebuf);
    p2build_k<<<NC, 256, 0, stream>>>(cbase, ebuf, csr_src, row_ptr, nin);

    // ---- one-time conversions ----
    int n4 = NN * 64;
    convfeat_k<<<(n4 + 255) / 256, 256, 0, stream>>>((const float4*)features, nout,
                                                     (h4*)hB, n4);
    convw_k<<<256, 256, 0, stream>>>(W0, Wt0, 256, 256);
    convw_k<<<256, 256, 0, stream>>>(W1, Wt1, 256, 256);
    convw_k<<<64, 256, 0, stream>>>(W2, Wt2, NCLS, 64);

    // ---- layer 0 (unfused control) ----
    agg256h_k<<<AGG_BLOCKS, 256, 0, stream>>>(row_ptr, csr_src, hB, hA, NN);
    gemm_lds_k<16, 1><<<GB, 512, 0, stream>>>(hA, Wt0, hB, NN, nin, nout, b0);

    // ---- layers 1+2 fused: gather h0 -> @W1 -> @W2 -> t3h (h1 never materialized) ----
    fused12_k<<<GB, 512, 0, stream>>>(row_ptr, csr_src, hB, Wt1, Wt2, t3h,
                                      nin, nout, b1);

    // ---- final aggregation + epilogue ----
    agg64h_k<<<AGG_BLOCKS, 256, 0, stream>>>(row_ptr, csr_src, t3h, nin, b2, out, NN);
}

// Round 10
// 898.753 us; speedup vs baseline: 1.1084x; 1.1084x over previous
//
#include <hip/hip_runtime.h>

#define NN 100000
#define NE 3200000
#define F 256
#define NCLS 40
#define NC 391              // coarse buckets of 256 dst nodes: 391*256 >= NN
#define NBLK_H 256          // histogram/scatter blocks (1 per CU); NE/NBLK_H = 12500
#define EPB (NE / NBLK_H)   // 12500 edges per block slice
#define CW 25000            // cnt_out words (NN/4, byte-packed)

using h4 = __attribute__((ext_vector_type(4))) _Float16;
using h8 = __attribute__((ext_vector_type(8))) _Float16;
using f4 = __attribute__((ext_vector_type(4))) float;

// ---------------- LDS-privatized histogram: out-degree (u8-packed) + coarse dst buckets ----------------
__global__ __launch_bounds__(256) void hist_k(const int* __restrict__ src,
                                              const int* __restrict__ dst,
                                              unsigned* __restrict__ pcnt,
                                              unsigned* __restrict__ pcc) {
    __shared__ unsigned hsrc[CW];     // 100 KB: per-node u8 counts, 4 nodes/word
    __shared__ unsigned hc[NC];       // 1.6 KB coarse bucket counts
    int t = threadIdx.x, b = blockIdx.x;
    for (int i = t; i < CW; i += 256) hsrc[i] = 0;
    for (int i = t; i < NC; i += 256) hc[i] = 0;
    __syncthreads();
    int beg = b * EPB, end = beg + EPB;
    for (int e = beg + t; e < end; e += 256) {
        int s = src[e];
        atomicAdd(&hsrc[s >> 2], 1u << (8 * (s & 3)));
        atomicAdd(&hc[dst[e] >> 8], 1u);
    }
    __syncthreads();
    unsigned* pc = pcnt + (size_t)b * CW;
    for (int i = t; i < CW; i += 256) pc[i] = hsrc[i];
    unsigned* pb = pcc + (size_t)b * NC;
    for (int i = t; i < NC; i += 256) pb[i] = hc[i];
}

// ---------------- stage A: reduce 32-block chunks of pcnt into packed u16 pairs ----------------
// cntlo[w] = s0 | s1<<16, cnthi[w] = s2 | s3<<16 (fields < 65536: max degree ~75)
__global__ __launch_bounds__(256) void redA_k(const unsigned* __restrict__ pcnt,
                                              unsigned* __restrict__ cntlo,
                                              unsigned* __restrict__ cnthi) {
    int w = blockIdx.x * 256 + threadIdx.x;
    if (w >= CW) return;
    int g = blockIdx.y;
    unsigned lo = 0, hi = 0;
    for (int b = g * 32; b < g * 32 + 32; b++) {
        unsigned v = pcnt[(size_t)b * CW + w];
        lo += (v & 255u) | (((v >> 8) & 255u) << 16);
        hi += ((v >> 16) & 255u) | ((v >> 24) << 16);
    }
    atomicAdd(&cntlo[w], lo);
    atomicAdd(&cnthi[w], hi);
}

// ---------------- stage B: unpack -> nout (4 nodes per thread) ----------------
__global__ void nout2_k(const unsigned* __restrict__ cntlo,
                        const unsigned* __restrict__ cnthi,
                        float* __restrict__ nout) {
    int w = blockIdx.x * blockDim.x + threadIdx.x;
    if (w >= CW) return;
    unsigned lo = cntlo[w], hi = cnthi[w];
    float4 o;
    o.x = rsqrtf(fmaxf((float)(lo & 0xFFFFu), 1.f));
    o.y = rsqrtf(fmaxf((float)(lo >> 16), 1.f));
    o.z = rsqrtf(fmaxf((float)(hi & 0xFFFFu), 1.f));
    o.w = rsqrtf(fmaxf((float)(hi >> 16), 1.f));
    *(float4*)(nout + w * 4) = o;
}

// ---------------- per-bucket scan over blocks ----------------
__global__ __launch_bounds__(256) void offsets_k(const unsigned* __restrict__ pcc,
                                                 unsigned* __restrict__ curoff,
                                                 unsigned* __restrict__ totals) {
    __shared__ unsigned sh[256];
    int c = blockIdx.x, t = threadIdx.x;
    unsigned v = pcc[(size_t)t * NC + c];
    sh[t] = v;
    __syncthreads();
    for (int off = 1; off < 256; off <<= 1) {
        unsigned x = (t >= off) ? sh[t - off] : 0;
        __syncthreads();
        sh[t] += x;
        __syncthreads();
    }
    curoff[(size_t)t * NC + c] = sh[t] - v;
    if (t == 255) totals[c] = sh[255];
}

// ---------------- exclusive scan of coarse totals -> cbase[NC+1] ----------------
__global__ __launch_bounds__(512) void base_k(const unsigned* __restrict__ totals,
                                              int* __restrict__ cbase) {
    __shared__ unsigned sh[512];
    int t = threadIdx.x;
    unsigned v = (t < NC) ? totals[t] : 0;
    sh[t] = v;
    __syncthreads();
    for (int off = 1; off < 512; off <<= 1) {
        unsigned x = (t >= off) ? sh[t - off] : 0;
        __syncthreads();
        sh[t] += x;
        __syncthreads();
    }
    if (t < NC) cbase[t] = (int)(sh[t] - v);
    if (t == 0) cbase[NC] = NE;
}

// ---------------- pass 1: scatter edges into coarse regions, LDS cursors ----------------
__global__ __launch_bounds__(256) void p1scat_k(const int* __restrict__ src,
                                                const int* __restrict__ dst,
                                                const int* __restrict__ cbase,
                                                const unsigned* __restrict__ curoff,
                                                unsigned* __restrict__ ebuf) {
    __shared__ int cur[NC];
    int t = threadIdx.x, b = blockIdx.x;
    for (int i = t; i < NC; i += 256)
        cur[i] = cbase[i] + (int)curoff[(size_t)b * NC + i];
    __syncthreads();
    int beg = b * EPB, end = beg + EPB;
    for (int e = beg + t; e < end; e += 256) {
        int d = dst[e];
        int p = atomicAdd(&cur[d >> 8], 1);
        ebuf[p] = (unsigned)src[e] | ((unsigned)(d & 255) << 17);
    }
}

// ---------------- pass 2: per-coarse-bucket fine sort -> csr_src, row_ptr, nin ----------------
__global__ __launch_bounds__(256) void p2build_k(const int* __restrict__ cbase,
                                                 const unsigned* __restrict__ ebuf,
                                                 int* __restrict__ csr_src,
                                                 int* __restrict__ row_ptr,
                                                 float* __restrict__ nin) {
    __shared__ int cnt[256], cur[256], sh[256];
    int c = blockIdx.x, t = threadIdx.x;
    int beg = cbase[c], end = cbase[c + 1];
    cnt[t] = 0;
    __syncthreads();
    for (int e = beg + t; e < end; e += 256)
        atomicAdd(&cnt[(ebuf[e] >> 17) & 255], 1);
    __syncthreads();
    int v = cnt[t];
    sh[t] = v;
    __syncthreads();
    for (int off = 1; off < 256; off <<= 1) {
        int x = (t >= off) ? sh[t - off] : 0;
        __syncthreads();
        sh[t] += x;
        __syncthreads();
    }
    int pref = sh[t] - v;
    int node = c * 256 + t;
    if (node <= NN) row_ptr[node] = beg + pref;
    if (node < NN)  nin[node] = rsqrtf(fmaxf((float)v, 1.f));
    cur[t] = pref;
    __syncthreads();
    for (int e = beg + t; e < end; e += 256) {
        unsigned w = ebuf[e];
        int p = atomicAdd(&cur[(w >> 17) & 255], 1);
        csr_src[beg + p] = (int)(w & 0x1FFFFu);
    }
}

// ---------------- features fp32 -> fp16, scaled by nout[row] ----------------
__global__ void convfeat_k(const float4* __restrict__ fin, const float* __restrict__ nout,
                           h4* __restrict__ fout, int n4) {
    int i = blockIdx.x * blockDim.x + threadIdx.x;
    if (i < n4) {
        float s = nout[i >> 6];
        float4 v = fin[i];
        h4 o;
        o[0] = (_Float16)(v.x * s);
        o[1] = (_Float16)(v.y * s);
        o[2] = (_Float16)(v.z * s);
        o[3] = (_Float16)(v.w * s);
        fout[i] = o;
    }
}

// ---------------- all weights fp32 -> fp16 transposed, one launch ----------------
__global__ void convw_all_k(const float* __restrict__ W0, const float* __restrict__ W1,
                            const float* __restrict__ W2,
                            _Float16* __restrict__ Wt0, _Float16* __restrict__ Wt1,
                            _Float16* __restrict__ Wt2) {
    int i = blockIdx.x * blockDim.x + threadIdx.x;
    if (i < 65536) {
        int n = i >> 8, k = i & 255;
        Wt0[i] = (_Float16)W0[k * 256 + n];
    } else if (i < 131072) {
        int j = i - 65536;
        int n = j >> 8, k = j & 255;
        Wt1[j] = (_Float16)W1[k * 256 + n];
    } else if (i < 147456) {
        int j = i - 131072;
        int n = j >> 8, k = j & 255;
        Wt2[j] = (n < NCLS) ? (_Float16)W2[k * NCLS + n] : (_Float16)0.0f;
    }
}

// ---------------- CSR aggregation, 256-wide: 32 lanes/edge, h8 loads ----------------
__global__ __launch_bounds__(256) void agg256h_k(
        const int* __restrict__ row_ptr, const int* __restrict__ csr_src,
        const _Float16* __restrict__ h, _Float16* __restrict__ agg, int nN) {
    int node = (blockIdx.x * blockDim.x + threadIdx.x) >> 6;
    int lane = threadIdx.x & 63;
    if (node >= nN) return;
    int half = lane >> 5, col = lane & 31;
    int beg = row_ptr[node], end = row_ptr[node + 1];
    f4 a[4][2];
#pragma unroll
    for (int u = 0; u < 4; u++) { a[u][0] = (f4){0,0,0,0}; a[u][1] = (f4){0,0,0,0}; }
    int e = beg;
    for (; e + 7 < end; e += 8) {
        int s[4];
#pragma unroll
        for (int u = 0; u < 4; u++) s[u] = csr_src[e + 2 * u + half];
        h8 v[4];
#pragma unroll
        for (int u = 0; u < 4; u++)
            v[u] = *(const h8*)(h + (size_t)s[u] * F + col * 8);
#pragma unroll
        for (int u = 0; u < 4; u++)
#pragma unroll
            for (int j = 0; j < 8; j++) a[u][j >> 2][j & 3] += (float)v[u][j];
    }
    for (int t = e + half; t < end; t += 2) {
        h8 v = *(const h8*)(h + (size_t)csr_src[t] * F + col * 8);
#pragma unroll
        for (int j = 0; j < 8; j++) a[0][j >> 2][j & 3] += (float)v[j];
    }
    float r[8];
#pragma unroll
    for (int j = 0; j < 8; j++)
        r[j] = (a[0][j >> 2][j & 3] + a[1][j >> 2][j & 3])
             + (a[2][j >> 2][j & 3] + a[3][j >> 2][j & 3]);
#pragma unroll
    for (int j = 0; j < 8; j++) r[j] += __shfl_xor(r[j], 32);
    if (half == 0) {
        h8 o;
#pragma unroll
        for (int j = 0; j < 8; j++) o[j] = (_Float16)r[j];
        *(h8*)(agg + (size_t)node * F + col * 8) = o;
    }
}

// ---------------- CSR aggregation, 64-wide + final epilogue ----------------
__global__ __launch_bounds__(256) void agg64h_k(
        const int* __restrict__ row_ptr, const int* __restrict__ csr_src,
        const _Float16* __restrict__ t3, const float* __restrict__ nin,
        const float* __restrict__ b2, float* __restrict__ out, int nN) {
    int node = (blockIdx.x * blockDim.x + threadIdx.x) >> 6;
    int lane = threadIdx.x & 63;
    if (node >= nN) return;
    int q = lane >> 4, c = lane & 15;
    int beg = row_ptr[node], end = row_ptr[node + 1];
    f4 a0 = {0,0,0,0}, a1 = {0,0,0,0};
    int e = beg;
    for (; e + 7 < end; e += 8) {
        int s0 = csr_src[e + q], s1 = csr_src[e + 4 + q];
        h4 v0 = *(const h4*)(t3 + (size_t)s0 * 64 + c * 4);
        h4 v1 = *(const h4*)(t3 + (size_t)s1 * 64 + c * 4);
#pragma unroll
        for (int j = 0; j < 4; j++) { a0[j] += (float)v0[j]; a1[j] += (float)v1[j]; }
    }
    for (int t = e + q; t < end; t += 4) {
        h4 v = *(const h4*)(t3 + (size_t)csr_src[t] * 64 + c * 4);
#pragma unroll
        for (int j = 0; j < 4; j++) a0[j] += (float)v[j];
    }
    float r[4];
#pragma unroll
    for (int j = 0; j < 4; j++) {
        r[j] = a0[j] + a1[j];
        r[j] += __shfl_xor(r[j], 16);
        r[j] += __shfl_xor(r[j], 32);
    }
    if (lane < 10) {
        float ni = nin[node];
        float4 o;
        o.x = r[0] * ni + b2[lane * 4 + 0];
        o.y = r[1] * ni + b2[lane * 4 + 1];
        o.z = r[2] * ni + b2[lane * 4 + 2];
        o.w = r[3] * ni + b2[lane * 4 + 3];
        *(float4*)(out + (size_t)node * NCLS + lane * 4) = o;
    }
}

// ---------------- LDS-resident f16 MFMA GEMM, 1024 threads (16 waves, 256 rows/block) ----------------
// Occupancy fix vs round-8: 512thr/8 waves @128KB LDS = 25% occ; 1024thr/16 waves = 50%.
// Identical MFMA order per row -> bitwise-identical results.
template <int NT, int EPI>
__global__ __launch_bounds__(1024) void gemm_lds_k(
        const _Float16* __restrict__ A, const _Float16* __restrict__ Wt,
        _Float16* __restrict__ C, int M,
        const float* __restrict__ nin, const float* __restrict__ nout,
        const float* __restrict__ bias) {
    constexpr int COLS = NT * 16;
    __shared__ _Float16 lds[COLS * 256];     // NT=16: 128 KiB, NT=4: 32 KiB
    char* ldsb = (char*)lds;

    const int tid  = threadIdx.x;
    const int lane = tid & 63;
    const int w    = tid >> 6;               // wave 0..15
    const int row0 = blockIdx.x * 256;

    // stage Wt -> LDS (swizzled): COLS*256 halfs = COLS*32 h8 chunks / 1024 threads
#pragma unroll
    for (int i = 0; i < COLS / 32; i++) {
        int idx  = (i * 1024 + tid) * 8;
        int byte = idx * 2;
        int row  = byte >> 9;
        int swz  = byte ^ ((row & 7) << 4);
        *(h8*)(ldsb + swz) = *(const h8*)(Wt + idx);
    }

    int arow = row0 + w * 16 + (lane & 15);
    if (arow >= M) arow = M - 1;
    const _Float16* Ap = A + (size_t)arow * 256 + (lane >> 4) * 8;
    h8 areg[8];
#pragma unroll
    for (int i = 0; i < 8; i++) areg[i] = *(const h8*)(Ap + i * 32);

    __syncthreads();

    f4 acc[NT];
#pragma unroll
    for (int n = 0; n < NT; n++) acc[n] = (f4){0.f, 0.f, 0.f, 0.f};

#pragma unroll
    for (int k0 = 0; k0 < 8; k0++) {
        int kb = (k0 * 32 + (lane >> 4) * 8) * 2;
#pragma unroll
        for (int n = 0; n < NT; n++) {
            int r    = n * 16 + (lane & 15);
            int byte = r * 512 + kb;
            int swz  = byte ^ ((r & 7) << 4);
            h8 bf = *(const h8*)(ldsb + swz);
            acc[n] = __builtin_amdgcn_mfma_f32_16x16x32_f16(areg[k0], bf, acc[n], 0, 0, 0);
        }
    }

    __syncthreads();   // all waves done reading Wt; reuse LDS for C transpose

    const int g  = lane >> 4;
    const int rb = row0 + w * 16 + g * 4;
    float si[4], so[4];
    if (EPI) {
#pragma unroll
        for (int r = 0; r < 4; r++) {
            int rr = rb + r; if (rr >= M) rr = M - 1;
            si[r] = nin[rr];
            so[r] = nout[rr];
        }
    }
    char* warea = ldsb + w * (16 * COLS * 2);   // per-wave 16-row tile; fits: 16*8KB=128KB (NT=16)
#pragma unroll
    for (int n = 0; n < NT; n++) {
        float bb = EPI ? bias[n * 16 + (lane & 15)] : 0.f;
#pragma unroll
        for (int r = 0; r < 4; r++) {
            float x = acc[n][r];
            if (EPI) x = fmaxf(x * si[r] + bb, 0.f) * so[r];
            int lrow = g * 4 + r;
            int lcol = n * 16 + (lane & 15);
            *(_Float16*)(warea + (size_t)(lrow * COLS + lcol) * 2) = (_Float16)x;
        }
    }

    _Float16* Crow = C + (size_t)(row0 + w * 16) * COLS;
#pragma unroll
    for (int i = 0; i < COLS / 32; i++) {
        int off  = i * 1024 + lane * 16;
        int lrow = off / (COLS * 2);
        int grow = row0 + w * 16 + lrow;
        h8 v = *(const h8*)(warea + off);
        if (grow < M) *(h8*)((char*)Crow + off) = v;
    }
}

extern "C" void kernel_launch(void* const* d_in, const int* in_sizes, int n_in,
                              void* d_out, int out_size, void* d_ws, size_t ws_size,
                              hipStream_t stream) {
    const float* features = (const float*)d_in[0];
    const int*   src      = (const int*)d_in[1];
    const int*   dst      = (const int*)d_in[2];
    const float* W0       = (const float*)d_in[3];
    const float* b0       = (const float*)d_in[4];
    const float* W1       = (const float*)d_in[5];
    const float* b1       = (const float*)d_in[6];
    const float* W2       = (const float*)d_in[7];
    const float* b2       = (const float*)d_in[8];
    float* out = (float*)d_out;

    // ---- workspace carve (16B-aligned sections) ----
    char* ws = (char*)d_ws;
    const size_t H_BYTES = (size_t)NN * F * 2;             // 51.2 MB
    _Float16* hA   = (_Float16*)(ws);
    _Float16* hB   = (_Float16*)(ws + H_BYTES);
    _Float16* t3h  = (_Float16*)(ws + 2 * H_BYTES);        // [NN,64] fp16
    char* q = ws + 2 * H_BYTES + (size_t)NN * 64 * 2;
    int* csr_src    = (int*)q;               q += (size_t)NE * 4;             // 12.8 MB
    unsigned* ebuf  = (unsigned*)q;          q += (size_t)NE * 4;             // 12.8 MB
    unsigned* pcnt  = (unsigned*)q;          q += (size_t)NBLK_H * CW * 4;    // 25.6 MB
    unsigned* pcc   = (unsigned*)q;          q += (size_t)NBLK_H * NC * 4 + 1024;
    unsigned* curoff= (unsigned*)q;          q += (size_t)NBLK_H * NC * 4 + 1024;
    char* p = q;
    const size_t SB = 401408;
    unsigned* totals = (unsigned*)(p + 0 * SB);
    int*   cbase   = (int*)(p + 1 * SB);
    int*   row_ptr = (int*)(p + 2 * SB);
    float* nout    = (float*)(p + 3 * SB);
    float* nin     = (float*)(p + 4 * SB);
    unsigned* cntlo = (unsigned*)(p + 5 * SB);             // CW u32 = 100 KB
    unsigned* cnthi = (unsigned*)(p + 6 * SB);
    _Float16* Wt0  = (_Float16*)(p + 7 * SB);              // 128 KB
    _Float16* Wt1  = (_Float16*)(p + 7 * SB + 131072);
    _Float16* Wt2  = (_Float16*)(p + 7 * SB + 262144);     // 32 KB

    const int AGG_BLOCKS = (NN * 64 + 255) / 256;
    const int GB = (NN + 255) / 256;                       // 391 gemm blocks (256 rows each)

    // ---- CSR build: LDS histograms -> offset scans -> 2-pass radix ----
    hipMemsetAsync(cntlo, 0, CW * 4, stream);
    hipMemsetAsync(cnthi, 0, CW * 4, stream);
    hist_k<<<NBLK_H, 256, 0, stream>>>(src, dst, pcnt, pcc);
    {
        dim3 rg((CW + 255) / 256, 8);
        redA_k<<<rg, 256, 0, stream>>>(pcnt, cntlo, cnthi);
    }
    nout2_k<<<(CW + 255) / 256, 256, 0, stream>>>(cntlo, cnthi, nout);
    offsets_k<<<NC, 256, 0, stream>>>(pcc, curoff, totals);
    base_k<<<1, 512, 0, stream>>>(totals, cbase);
    p1scat_k<<<NBLK_H, 256, 0, stream>>>(src, dst, cbase, curoff, ebuf);
    p2build_k<<<NC, 256, 0, stream>>>(cbase, ebuf, csr_src, row_ptr, nin);

    // ---- one-time conversions ----
    int n4 = NN * 64;
    convfeat_k<<<(n4 + 255) / 256, 256, 0, stream>>>((const float4*)features, nout,
                                                     (h4*)hB, n4);
    convw_all_k<<<576, 256, 0, stream>>>(W0, W1, W2, Wt0, Wt1, Wt2);

    // ---- layer 0 ----
    agg256h_k<<<AGG_BLOCKS, 256, 0, stream>>>(row_ptr, csr_src, hB, hA, NN);
    gemm_lds_k<16, 1><<<GB, 1024, 0, stream>>>(hA, Wt0, hB, NN, nin, nout, b0);

    // ---- layer 1 ----
    agg256h_k<<<AGG_BLOCKS, 256, 0, stream>>>(row_ptr, csr_src, hB, hA, NN);
    gemm_lds_k<16, 1><<<GB, 1024, 0, stream>>>(hA, Wt1, hB, NN, nin, nout, b1);

    // ---- layer 2 ----
    gemm_lds_k<4, 0><<<GB, 1024, 0, stream>>>(hB, Wt2, t3h, NN, nullptr, nullptr, nullptr);
    agg64h_k<<<AGG_BLOCKS, 256, 0, stream>>>(row_ptr, csr_src, t3h, nin, b2, out, NN);
}

// Round 11
// 840.745 us; speedup vs baseline: 1.1849x; 1.0690x over previous
//
#include <hip/hip_runtime.h>

#define NN 100000
#define NE 3200000
#define F 256
#define NCLS 40
#define NC 391              // coarse buckets of 256 dst nodes: 391*256 >= NN
#define NBLK_H 256          // histogram/scatter blocks; NE/NBLK_H = 12500
#define EPB (NE / NBLK_H)   // 12500 edges per block slice
#define CW 25000            // cnt_out words (NN/4, byte-packed)

using h4 = __attribute__((ext_vector_type(4))) _Float16;
using h8 = __attribute__((ext_vector_type(8))) _Float16;
using f4 = __attribute__((ext_vector_type(4))) float;

// ---------------- LDS-privatized histogram (512 thr for TLP): out-degree u8 + coarse buckets ----------------
__global__ __launch_bounds__(512) void hist_k(const int* __restrict__ src,
                                              const int* __restrict__ dst,
                                              unsigned* __restrict__ pcnt,
                                              unsigned* __restrict__ pcc) {
    __shared__ unsigned hsrc[CW];     // 100 KB: per-node u8 counts, 4 nodes/word
    __shared__ unsigned hc[NC];       // 1.6 KB coarse bucket counts
    int t = threadIdx.x, b = blockIdx.x;
    for (int i = t; i < CW; i += 512) hsrc[i] = 0;
    for (int i = t; i < NC; i += 512) hc[i] = 0;
    __syncthreads();
    int beg = b * EPB, end = beg + EPB;
    for (int e = beg + t; e < end; e += 512) {
        int s = src[e];
        atomicAdd(&hsrc[s >> 2], 1u << (8 * (s & 3)));
        atomicAdd(&hc[dst[e] >> 8], 1u);
    }
    __syncthreads();
    unsigned* pc = pcnt + (size_t)b * CW;
    for (int i = t; i < CW; i += 512) pc[i] = hsrc[i];
    unsigned* pb = pcc + (size_t)b * NC;
    for (int i = t; i < NC; i += 512) pb[i] = hc[i];
}

// ---------------- stage A: reduce 32-block chunks of pcnt into packed u16 pairs ----------------
__global__ __launch_bounds__(256) void redA_k(const unsigned* __restrict__ pcnt,
                                              unsigned* __restrict__ cntlo,
                                              unsigned* __restrict__ cnthi) {
    int w = blockIdx.x * 256 + threadIdx.x;
    if (w >= CW) return;
    int g = blockIdx.y;
    unsigned lo = 0, hi = 0;
    for (int b = g * 32; b < g * 32 + 32; b++) {
        unsigned v = pcnt[(size_t)b * CW + w];
        lo += (v & 255u) | (((v >> 8) & 255u) << 16);
        hi += ((v >> 16) & 255u) | ((v >> 24) << 16);
    }
    atomicAdd(&cntlo[w], lo);
    atomicAdd(&cnthi[w], hi);
}

// ---------------- stage B: unpack -> nout ----------------
__global__ void nout2_k(const unsigned* __restrict__ cntlo,
                        const unsigned* __restrict__ cnthi,
                        float* __restrict__ nout) {
    int w = blockIdx.x * blockDim.x + threadIdx.x;
    if (w >= CW) return;
    unsigned lo = cntlo[w], hi = cnthi[w];
    float4 o;
    o.x = rsqrtf(fmaxf((float)(lo & 0xFFFFu), 1.f));
    o.y = rsqrtf(fmaxf((float)(lo >> 16), 1.f));
    o.z = rsqrtf(fmaxf((float)(hi & 0xFFFFu), 1.f));
    o.w = rsqrtf(fmaxf((float)(hi >> 16), 1.f));
    *(float4*)(nout + w * 4) = o;
}

// ---------------- per-bucket scan over blocks ----------------
__global__ __launch_bounds__(256) void offsets_k(const unsigned* __restrict__ pcc,
                                                 unsigned* __restrict__ curoff,
                                                 unsigned* __restrict__ totals) {
    __shared__ unsigned sh[256];
    int c = blockIdx.x, t = threadIdx.x;
    unsigned v = pcc[(size_t)t * NC + c];
    sh[t] = v;
    __syncthreads();
    for (int off = 1; off < 256; off <<= 1) {
        unsigned x = (t >= off) ? sh[t - off] : 0;
        __syncthreads();
        sh[t] += x;
        __syncthreads();
    }
    curoff[(size_t)t * NC + c] = sh[t] - v;
    if (t == 255) totals[c] = sh[255];
}

// ---------------- exclusive scan of coarse totals -> cbase[NC+1] ----------------
__global__ __launch_bounds__(512) void base_k(const unsigned* __restrict__ totals,
                                              int* __restrict__ cbase) {
    __shared__ unsigned sh[512];
    int t = threadIdx.x;
    unsigned v = (t < NC) ? totals[t] : 0;
    sh[t] = v;
    __syncthreads();
    for (int off = 1; off < 512; off <<= 1) {
        unsigned x = (t >= off) ? sh[t - off] : 0;
        __syncthreads();
        sh[t] += x;
        __syncthreads();
    }
    if (t < NC) cbase[t] = (int)(sh[t] - v);
    if (t == 0) cbase[NC] = NE;
}

// ---------------- pass 1: scatter into coarse regions, LDS cursors (512 thr) ----------------
__global__ __launch_bounds__(512) void p1scat_k(const int* __restrict__ src,
                                                const int* __restrict__ dst,
                                                const int* __restrict__ cbase,
                                                const unsigned* __restrict__ curoff,
                                                unsigned* __restrict__ ebuf) {
    __shared__ int cur[NC];
    int t = threadIdx.x, b = blockIdx.x;
    for (int i = t; i < NC; i += 512)
        cur[i] = cbase[i] + (int)curoff[(size_t)b * NC + i];
    __syncthreads();
    int beg = b * EPB, end = beg + EPB;
    for (int e = beg + t; e < end; e += 512) {
        int d = dst[e];
        int p = atomicAdd(&cur[d >> 8], 1);
        ebuf[p] = (unsigned)src[e] | ((unsigned)(d & 255) << 17);
    }
}

// ---------------- pass 2: per-bucket fine sort -> csr_src, row_ptr, nin (512 thr) ----------------
__global__ __launch_bounds__(512) void p2build_k(const int* __restrict__ cbase,
                                                 const unsigned* __restrict__ ebuf,
                                                 int* __restrict__ csr_src,
                                                 int* __restrict__ row_ptr,
                                                 float* __restrict__ nin) {
    __shared__ int cnt[256], cur[256], sh[256];
    int c = blockIdx.x, t = threadIdx.x;
    int beg = cbase[c], end = cbase[c + 1];
    if (t < 256) cnt[t] = 0;
    __syncthreads();
    for (int e = beg + t; e < end; e += 512)
        atomicAdd(&cnt[(ebuf[e] >> 17) & 255], 1);
    __syncthreads();
    int v = 0;
    if (t < 256) { v = cnt[t]; sh[t] = v; }
    __syncthreads();
    for (int off = 1; off < 256; off <<= 1) {
        int x = (t < 256 && t >= off) ? sh[t - off] : 0;
        __syncthreads();
        if (t < 256) sh[t] += x;
        __syncthreads();
    }
    if (t < 256) {
        int pref = sh[t] - v;
        int node = c * 256 + t;
        if (node <= NN) row_ptr[node] = beg + pref;
        if (node < NN)  nin[node] = rsqrtf(fmaxf((float)v, 1.f));
        cur[t] = pref;
    }
    if (c == 0 && t == 0) row_ptr[NN] = NE;
    __syncthreads();
    for (int e = beg + t; e < end; e += 512) {
        unsigned w = ebuf[e];
        int p = atomicAdd(&cur[(w >> 17) & 255], 1);
        csr_src[beg + p] = (int)(w & 0x1FFFFu);
    }
}

// ---------------- fused conversions: features*nout -> fp16, all weights -> fp16^T ----------------
__global__ void conv_fused_k(const float4* __restrict__ fin, const float* __restrict__ nout,
                             h4* __restrict__ fout,
                             const float* __restrict__ W0, const float* __restrict__ W1,
                             const float* __restrict__ W2,
                             _Float16* __restrict__ Wt0, _Float16* __restrict__ Wt1,
                             _Float16* __restrict__ Wt2) {
    int i = blockIdx.x * blockDim.x + threadIdx.x;
    const int N4 = NN * 64;
    if (i < N4) {
        float s = nout[i >> 6];
        float4 v = fin[i];
        h4 o;
        o[0] = (_Float16)(v.x * s);
        o[1] = (_Float16)(v.y * s);
        o[2] = (_Float16)(v.z * s);
        o[3] = (_Float16)(v.w * s);
        fout[i] = o;
    } else {
        int j = i - N4;
        if (j < 65536) {
            int n = j >> 8, k = j & 255;
            Wt0[j] = (_Float16)W0[k * 256 + n];
        } else if (j < 131072) {
            int jj = j - 65536;
            int n = jj >> 8, k = jj & 255;
            Wt1[jj] = (_Float16)W1[k * 256 + n];
        } else if (j < 147456) {
            int jj = j - 131072;
            int n = jj >> 8, k = jj & 255;
            Wt2[jj] = (n < NCLS) ? (_Float16)W2[k * NCLS + n] : (_Float16)0.0f;
        }
    }
}

// ---------------- CSR aggregation, 256-wide: 32 lanes/edge, h8 loads ----------------
__global__ __launch_bounds__(256) void agg256h_k(
        const int* __restrict__ row_ptr, const int* __restrict__ csr_src,
        const _Float16* __restrict__ h, _Float16* __restrict__ agg, int nN) {
    int node = (blockIdx.x * blockDim.x + threadIdx.x) >> 6;
    int lane = threadIdx.x & 63;
    if (node >= nN) return;
    int half = lane >> 5, col = lane & 31;
    int beg = row_ptr[node], end = row_ptr[node + 1];
    f4 a[4][2];
#pragma unroll
    for (int u = 0; u < 4; u++) { a[u][0] = (f4){0,0,0,0}; a[u][1] = (f4){0,0,0,0}; }
    int e = beg;
    for (; e + 7 < end; e += 8) {
        int s[4];
#pragma unroll
        for (int u = 0; u < 4; u++) s[u] = csr_src[e + 2 * u + half];
        h8 v[4];
#pragma unroll
        for (int u = 0; u < 4; u++)
            v[u] = *(const h8*)(h + (size_t)s[u] * F + col * 8);
#pragma unroll
        for (int u = 0; u < 4; u++)
#pragma unroll
            for (int j = 0; j < 8; j++) a[u][j >> 2][j & 3] += (float)v[u][j];
    }
    for (int t = e + half; t < end; t += 2) {
        h8 v = *(const h8*)(h + (size_t)csr_src[t] * F + col * 8);
#pragma unroll
        for (int j = 0; j < 8; j++) a[0][j >> 2][j & 3] += (float)v[j];
    }
    float r[8];
#pragma unroll
    for (int j = 0; j < 8; j++)
        r[j] = (a[0][j >> 2][j & 3] + a[1][j >> 2][j & 3])
             + (a[2][j >> 2][j & 3] + a[3][j >> 2][j & 3]);
#pragma unroll
    for (int j = 0; j < 8; j++) r[j] += __shfl_xor(r[j], 32);
    if (half == 0) {
        h8 o;
#pragma unroll
        for (int j = 0; j < 8; j++) o[j] = (_Float16)r[j];
        *(h8*)(agg + (size_t)node * F + col * 8) = o;
    }
}

// ---------------- CSR aggregation, 64-wide: 8 lanes/edge, h8 loads + final epilogue ----------------
__global__ __launch_bounds__(256) void agg64h_k(
        const int* __restrict__ row_ptr, const int* __restrict__ csr_src,
        const _Float16* __restrict__ t3, const float* __restrict__ nin,
        const float* __restrict__ b2, float* __restrict__ out, int nN) {
    int node = (blockIdx.x * blockDim.x + threadIdx.x) >> 6;
    int lane = threadIdx.x & 63;
    if (node >= nN) return;
    int grp = lane >> 3, c = lane & 7;     // c owns halfs c*8..c*8+7 (16B)
    int beg = row_ptr[node], end = row_ptr[node + 1];
    float a0[8], a1[8];
#pragma unroll
    for (int j = 0; j < 8; j++) { a0[j] = 0.f; a1[j] = 0.f; }
    int e = beg;
    for (; e + 15 < end; e += 16) {        // 16 edges/iter, 2 per group
        int s0 = csr_src[e + grp], s1 = csr_src[e + 8 + grp];
        h8 v0 = *(const h8*)(t3 + (size_t)s0 * 64 + c * 8);
        h8 v1 = *(const h8*)(t3 + (size_t)s1 * 64 + c * 8);
#pragma unroll
        for (int j = 0; j < 8; j++) { a0[j] += (float)v0[j]; a1[j] += (float)v1[j]; }
    }
    for (int t = e + grp; t < end; t += 8) {
        h8 v = *(const h8*)(t3 + (size_t)csr_src[t] * 64 + c * 8);
#pragma unroll
        for (int j = 0; j < 8; j++) a0[j] += (float)v[j];
    }
    float r[8];
#pragma unroll
    for (int j = 0; j < 8; j++) {
        r[j] = a0[j] + a1[j];
        r[j] += __shfl_xor(r[j], 8);
        r[j] += __shfl_xor(r[j], 16);
        r[j] += __shfl_xor(r[j], 32);
    }
    if (grp == 0 && c < 5) {               // cols c*8..c*8+7 < 40
        float ni = nin[node];
        float4 o;
        o.x = r[0] * ni + b2[c * 8 + 0];
        o.y = r[1] * ni + b2[c * 8 + 1];
        o.z = r[2] * ni + b2[c * 8 + 2];
        o.w = r[3] * ni + b2[c * 8 + 3];
        *(float4*)(out + (size_t)node * NCLS + c * 8) = o;
        o.x = r[4] * ni + b2[c * 8 + 4];
        o.y = r[5] * ni + b2[c * 8 + 5];
        o.z = r[6] * ni + b2[c * 8 + 6];
        o.w = r[7] * ni + b2[c * 8 + 7];
        *(float4*)(out + (size_t)node * NCLS + c * 8 + 4) = o;
    }
}

// ---------------- LDS-resident f16 MFMA GEMM, 1024 threads (16 waves, 256 rows/block) ----------------
template <int NT, int EPI>
__global__ __launch_bounds__(1024) void gemm_lds_k(
        const _Float16* __restrict__ A, const _Float16* __restrict__ Wt,
        _Float16* __restrict__ C, int M,
        const float* __restrict__ nin, const float* __restrict__ nout,
        const float* __restrict__ bias) {
    constexpr int COLS = NT * 16;
    __shared__ _Float16 lds[COLS * 256];     // NT=16: 128 KiB, NT=4: 32 KiB
    char* ldsb = (char*)lds;

    const int tid  = threadIdx.x;
    const int lane = tid & 63;
    const int w    = tid >> 6;               // wave 0..15
    const int row0 = blockIdx.x * 256;

#pragma unroll
    for (int i = 0; i < COLS / 32; i++) {
        int idx  = (i * 1024 + tid) * 8;
        int byte = idx * 2;
        int row  = byte >> 9;
        int swz  = byte ^ ((row & 7) << 4);
        *(h8*)(ldsb + swz) = *(const h8*)(Wt + idx);
    }

    int arow = row0 + w * 16 + (lane & 15);
    if (arow >= M) arow = M - 1;
    const _Float16* Ap = A + (size_t)arow * 256 + (lane >> 4) * 8;
    h8 areg[8];
#pragma unroll
    for (int i = 0; i < 8; i++) areg[i] = *(const h8*)(Ap + i * 32);

    __syncthreads();

    f4 acc[NT];
#pragma unroll
    for (int n = 0; n < NT; n++) acc[n] = (f4){0.f, 0.f, 0.f, 0.f};

#pragma unroll
    for (int k0 = 0; k0 < 8; k0++) {
        int kb = (k0 * 32 + (lane >> 4) * 8) * 2;
#pragma unroll
        for (int n = 0; n < NT; n++) {
            int r    = n * 16 + (lane & 15);
            int byte = r * 512 + kb;
            int swz  = byte ^ ((r & 7) << 4);
            h8 bf = *(const h8*)(ldsb + swz);
            acc[n] = __builtin_amdgcn_mfma_f32_16x16x32_f16(areg[k0], bf, acc[n], 0, 0, 0);
        }
    }

    __syncthreads();

    const int g  = lane >> 4;
    const int rb = row0 + w * 16 + g * 4;
    float si[4], so[4];
    if (EPI) {
#pragma unroll
        for (int r = 0; r < 4; r++) {
            int rr = rb + r; if (rr >= M) rr = M - 1;
            si[r] = nin[rr];
            so[r] = nout[rr];
        }
    }
    char* warea = ldsb + w * (16 * COLS * 2);
#pragma unroll
    for (int n = 0; n < NT; n++) {
        float bb = EPI ? bias[n * 16 + (lane & 15)] : 0.f;
#pragma unroll
        for (int r = 0; r < 4; r++) {
            float x = acc[n][r];
            if (EPI) x = fmaxf(x * si[r] + bb, 0.f) * so[r];
            int lrow = g * 4 + r;
            int lcol = n * 16 + (lane & 15);
            *(_Float16*)(warea + (size_t)(lrow * COLS + lcol) * 2) = (_Float16)x;
        }
    }

    _Float16* Crow = C + (size_t)(row0 + w * 16) * COLS;
#pragma unroll
    for (int i = 0; i < COLS / 32; i++) {
        int off  = i * 1024 + lane * 16;
        int lrow = off / (COLS * 2);
        int grow = row0 + w * 16 + lrow;
        h8 v = *(const h8*)(warea + off);
        if (grow < M) *(h8*)((char*)Crow + off) = v;
    }
}

extern "C" void kernel_launch(void* const* d_in, const int* in_sizes, int n_in,
                              void* d_out, int out_size, void* d_ws, size_t ws_size,
                              hipStream_t stream) {
    const float* features = (const float*)d_in[0];
    const int*   src      = (const int*)d_in[1];
    const int*   dst      = (const int*)d_in[2];
    const float* W0       = (const float*)d_in[3];
    const float* b0       = (const float*)d_in[4];
    const float* W1       = (const float*)d_in[5];
    const float* b1       = (const float*)d_in[6];
    const float* W2       = (const float*)d_in[7];
    const float* b2       = (const float*)d_in[8];
    float* out = (float*)d_out;

    // ---- workspace carve (16B-aligned sections) ----
    char* ws = (char*)d_ws;
    const size_t H_BYTES = (size_t)NN * F * 2;             // 51.2 MB
    _Float16* hA   = (_Float16*)(ws);
    _Float16* hB   = (_Float16*)(ws + H_BYTES);
    _Float16* t3h  = (_Float16*)(ws + 2 * H_BYTES);        // [NN,64] fp16
    char* q = ws + 2 * H_BYTES + (size_t)NN * 64 * 2;
    int* csr_src    = (int*)q;               q += (size_t)NE * 4;             // 12.8 MB
    unsigned* ebuf  = (unsigned*)q;          q += (size_t)NE * 4;             // 12.8 MB
    unsigned* pcnt  = (unsigned*)q;          q += (size_t)NBLK_H * CW * 4;    // 25.6 MB
    unsigned* pcc   = (unsigned*)q;          q += (size_t)NBLK_H * NC * 4 + 1024;
    unsigned* curoff= (unsigned*)q;          q += (size_t)NBLK_H * NC * 4 + 1024;
    char* p = q;
    const size_t SB = 401408;
    unsigned* totals = (unsigned*)(p + 0 * SB);
    int*   cbase   = (int*)(p + 1 * SB);
    int*   row_ptr = (int*)(p + 2 * SB);
    float* nout    = (float*)(p + 3 * SB);
    float* nin     = (float*)(p + 4 * SB);
    unsigned* cntlo = (unsigned*)(p + 5 * SB);
    unsigned* cnthi = (unsigned*)(p + 6 * SB);
    _Float16* Wt0  = (_Float16*)(p + 7 * SB);              // 128 KB
    _Float16* Wt1  = (_Float16*)(p + 7 * SB + 131072);
    _Float16* Wt2  = (_Float16*)(p + 7 * SB + 262144);     // 32 KB

    const int AGG_BLOCKS = (NN * 64 + 255) / 256;
    const int GB = (NN + 255) / 256;                       // 391 gemm blocks

    // ---- CSR build: LDS histograms -> offset scans -> 2-pass radix ----
    hipMemsetAsync(cntlo, 0, CW * 4, stream);
    hipMemsetAsync(cnthi, 0, CW * 4, stream);
    hist_k<<<NBLK_H, 512, 0, stream>>>(src, dst, pcnt, pcc);
    {
        dim3 rg((CW + 255) / 256, 8);
        redA_k<<<rg, 256, 0, stream>>>(pcnt, cntlo, cnthi);
    }
    nout2_k<<<(CW + 255) / 256, 256, 0, stream>>>(cntlo, cnthi, nout);
    offsets_k<<<NC, 256, 0, stream>>>(pcc, curoff, totals);
    base_k<<<1, 512, 0, stream>>>(totals, cbase);
    p1scat_k<<<NBLK_H, 512, 0, stream>>>(src, dst, cbase, curoff, ebuf);
    p2build_k<<<NC, 512, 0, stream>>>(cbase, ebuf, csr_src, row_ptr, nin);

    // ---- fused one-time conversions ----
    {
        int total = NN * 64 + 147456;
        conv_fused_k<<<(total + 255) / 256, 256, 0, stream>>>(
            (const float4*)features, nout, (h4*)hB, W0, W1, W2, Wt0, Wt1, Wt2);
    }

    // ---- layer 0 ----
    agg256h_k<<<AGG_BLOCKS, 256, 0, stream>>>(row_ptr, csr_src, hB, hA, NN);
    gemm_lds_k<16, 1><<<GB, 1024, 0, stream>>>(hA, Wt0, hB, NN, nin, nout, b0);

    // ---- layer 1 ----
    agg256h_k<<<AGG_BLOCKS, 256, 0, stream>>>(row_ptr, csr_src, hB, hA, NN);
    gemm_lds_k<16, 1><<<GB, 1024, 0, stream>>>(hA, Wt1, hB, NN, nin, nout, b1);

    // ---- layer 2 ----
    gemm_lds_k<4, 0><<<GB, 1024, 0, stream>>>(hB, Wt2, t3h, NN, nullptr, nullptr, nullptr);
    agg64h_k<<<AGG_BLOCKS, 256, 0, stream>>>(row_ptr, csr_src, t3h, nin, b2, out, NN);
}

// Round 12
// 837.042 us; speedup vs baseline: 1.1901x; 1.0044x over previous
//
#include <hip/hip_runtime.h>

#define NN 100000
#define NE 3200000
#define F 256
#define NCLS 40
#define NC 391              // coarse buckets of 256 dst nodes: 391*256 >= NN
#define NBLK_H 256          // histogram/scatter blocks; NE/NBLK_H = 12500
#define EPB (NE / NBLK_H)   // 12500 edges per block slice
#define CW 25000            // cnt_out words (NN/4, byte-packed)

using h4 = __attribute__((ext_vector_type(4))) _Float16;
using h8 = __attribute__((ext_vector_type(8))) _Float16;
using f4 = __attribute__((ext_vector_type(4))) float;

// ---------------- LDS-privatized histogram (512 thr): out-degree u8 + coarse buckets ----------------
__global__ __launch_bounds__(512) void hist_k(const int* __restrict__ src,
                                              const int* __restrict__ dst,
                                              unsigned* __restrict__ pcnt,
                                              unsigned* __restrict__ pcc) {
    __shared__ unsigned hsrc[CW];     // 100 KB
    __shared__ unsigned hc[NC];
    int t = threadIdx.x, b = blockIdx.x;
    for (int i = t; i < CW; i += 512) hsrc[i] = 0;
    for (int i = t; i < NC; i += 512) hc[i] = 0;
    __syncthreads();
    int beg = b * EPB, end = beg + EPB;
    for (int e = beg + t; e < end; e += 512) {
        int s = src[e];
        atomicAdd(&hsrc[s >> 2], 1u << (8 * (s & 3)));
        atomicAdd(&hc[dst[e] >> 8], 1u);
    }
    __syncthreads();
    unsigned* pc = pcnt + (size_t)b * CW;
    for (int i = t; i < CW; i += 512) pc[i] = hsrc[i];
    unsigned* pb = pcc + (size_t)b * NC;
    for (int i = t; i < NC; i += 512) pb[i] = hc[i];
}

// ---------------- stage A: per-group partial sums (atomic-free, no memset needed) ----------------
__global__ __launch_bounds__(256) void redA_k(const unsigned* __restrict__ pcnt,
                                              unsigned* __restrict__ pl,
                                              unsigned* __restrict__ ph) {
    int w = blockIdx.x * 256 + threadIdx.x;
    if (w >= CW) return;
    int g = blockIdx.y;
    unsigned lo = 0, hi = 0;
    for (int b = g * 32; b < g * 32 + 32; b++) {
        unsigned v = pcnt[(size_t)b * CW + w];
        lo += (v & 255u) | (((v >> 8) & 255u) << 16);
        hi += ((v >> 16) & 255u) | ((v >> 24) << 16);
    }
    pl[(size_t)g * CW + w] = lo;
    ph[(size_t)g * CW + w] = hi;
}

// ---------------- stage B: sum 8 groups, unpack -> nout ----------------
__global__ void nout2_k(const unsigned* __restrict__ pl, const unsigned* __restrict__ ph,
                        float* __restrict__ nout) {
    int w = blockIdx.x * blockDim.x + threadIdx.x;
    if (w >= CW) return;
    unsigned lo = 0, hi = 0;
#pragma unroll
    for (int g = 0; g < 8; g++) { lo += pl[(size_t)g * CW + w]; hi += ph[(size_t)g * CW + w]; }
    float4 o;
    o.x = rsqrtf(fmaxf((float)(lo & 0xFFFFu), 1.f));
    o.y = rsqrtf(fmaxf((float)(lo >> 16), 1.f));
    o.z = rsqrtf(fmaxf((float)(hi & 0xFFFFu), 1.f));
    o.w = rsqrtf(fmaxf((float)(hi >> 16), 1.f));
    *(float4*)(nout + w * 4) = o;
}

// ---------------- per-bucket scan over blocks ----------------
__global__ __launch_bounds__(256) void offsets_k(const unsigned* __restrict__ pcc,
                                                 unsigned* __restrict__ curoff,
                                                 unsigned* __restrict__ totals) {
    __shared__ unsigned sh[256];
    int c = blockIdx.x, t = threadIdx.x;
    unsigned v = pcc[(size_t)t * NC + c];
    sh[t] = v;
    __syncthreads();
    for (int off = 1; off < 256; off <<= 1) {
        unsigned x = (t >= off) ? sh[t - off] : 0;
        __syncthreads();
        sh[t] += x;
        __syncthreads();
    }
    curoff[(size_t)t * NC + c] = sh[t] - v;
    if (t == 255) totals[c] = sh[255];
}

// ---------------- exclusive scan of coarse totals -> cbase[NC+1] ----------------
__global__ __launch_bounds__(512) void base_k(const unsigned* __restrict__ totals,
                                              int* __restrict__ cbase) {
    __shared__ unsigned sh[512];
    int t = threadIdx.x;
    unsigned v = (t < NC) ? totals[t] : 0;
    sh[t] = v;
    __syncthreads();
    for (int off = 1; off < 512; off <<= 1) {
        unsigned x = (t >= off) ? sh[t - off] : 0;
        __syncthreads();
        sh[t] += x;
        __syncthreads();
    }
    if (t < NC) cbase[t] = (int)(sh[t] - v);
    if (t == 0) cbase[NC] = NE;
}

// ---------------- pass 1: scatter into coarse regions, LDS cursors (512 thr) ----------------
__global__ __launch_bounds__(512) void p1scat_k(const int* __restrict__ src,
                                                const int* __restrict__ dst,
                                                const int* __restrict__ cbase,
                                                const unsigned* __restrict__ curoff,
                                                unsigned* __restrict__ ebuf) {
    __shared__ int cur[NC];
    int t = threadIdx.x, b = blockIdx.x;
    for (int i = t; i < NC; i += 512)
        cur[i] = cbase[i] + (int)curoff[(size_t)b * NC + i];
    __syncthreads();
    int beg = b * EPB, end = beg + EPB;
    for (int e = beg + t; e < end; e += 512) {
        int d = dst[e];
        int p = atomicAdd(&cur[d >> 8], 1);
        ebuf[p] = (unsigned)src[e] | ((unsigned)(d & 255) << 17);
    }
}

// ---------------- pass 2: per-bucket fine sort -> csr_src, row_ptr, nin (512 thr) ----------------
__global__ __launch_bounds__(512) void p2build_k(const int* __restrict__ cbase,
                                                 const unsigned* __restrict__ ebuf,
                                                 int* __restrict__ csr_src,
                                                 int* __restrict__ row_ptr,
                                                 float* __restrict__ nin) {
    __shared__ int cnt[256], cur[256], sh[256];
    int c = blockIdx.x, t = threadIdx.x;
    int beg = cbase[c], end = cbase[c + 1];
    if (t < 256) cnt[t] = 0;
    __syncthreads();
    for (int e = beg + t; e < end; e += 512)
        atomicAdd(&cnt[(ebuf[e] >> 17) & 255], 1);
    __syncthreads();
    int v = 0;
    if (t < 256) { v = cnt[t]; sh[t] = v; }
    __syncthreads();
    for (int off = 1; off < 256; off <<= 1) {
        int x = (t < 256 && t >= off) ? sh[t - off] : 0;
        __syncthreads();
        if (t < 256) sh[t] += x;
        __syncthreads();
    }
    if (t < 256) {
        int pref = sh[t] - v;
        int node = c * 256 + t;
        if (node <= NN) row_ptr[node] = beg + pref;
        if (node < NN)  nin[node] = rsqrtf(fmaxf((float)v, 1.f));
        cur[t] = pref;
    }
    if (c == 0 && t == 0) row_ptr[NN] = NE;
    __syncthreads();
    for (int e = beg + t; e < end; e += 512) {
        unsigned w = ebuf[e];
        int p = atomicAdd(&cur[(w >> 17) & 255], 1);
        csr_src[beg + p] = (int)(w & 0x1FFFFu);
    }
}

// ---------------- fused conversions: features*nout -> fp16; weights -> fp16^T PRE-SWIZZLED ----------------
// Wt layout: Wts[n*256 + (k ^ ((n&7)<<3))] = W[k][n]  (so GEMM stages LDS linearly,
// reads with byte ^= ((row&7)<<4) — content-equivalent to round-11, stage addressing simpler)
__global__ void conv_fused_k(const float4* __restrict__ fin, const float* __restrict__ nout,
                             h4* __restrict__ fout,
                             const float* __restrict__ W0, const float* __restrict__ W1,
                             const float* __restrict__ W2,
                             _Float16* __restrict__ Wt0, _Float16* __restrict__ Wt1,
                             _Float16* __restrict__ Wt2) {
    int i = blockIdx.x * blockDim.x + threadIdx.x;
    const int N4 = NN * 64;
    if (i < N4) {
        float s = nout[i >> 6];
        float4 v = fin[i];
        h4 o;
        o[0] = (_Float16)(v.x * s);
        o[1] = (_Float16)(v.y * s);
        o[2] = (_Float16)(v.z * s);
        o[3] = (_Float16)(v.w * s);
        fout[i] = o;
    } else {
        int j = i - N4;
        if (j < 65536) {
            int n = j >> 8, k = (j & 255) ^ ((n & 7) << 3);
            Wt0[j] = (_Float16)W0[k * 256 + n];
        } else if (j < 131072) {
            int jj = j - 65536;
            int n = jj >> 8, k = (jj & 255) ^ ((n & 7) << 3);
            Wt1[jj] = (_Float16)W1[k * 256 + n];
        } else if (j < 147456) {
            int jj = j - 131072;
            int n = jj >> 8, k = (jj & 255) ^ ((n & 7) << 3);
            Wt2[jj] = (n < NCLS) ? (_Float16)W2[k * NCLS + n] : (_Float16)0.0f;
        }
    }
}

// ---------------- CSR aggregation, 256-wide: 32 lanes/edge, h8 loads ----------------
__global__ __launch_bounds__(256) void agg256h_k(
        const int* __restrict__ row_ptr, const int* __restrict__ csr_src,
        const _Float16* __restrict__ h, _Float16* __restrict__ agg, int nN) {
    int node = (blockIdx.x * blockDim.x + threadIdx.x) >> 6;
    int lane = threadIdx.x & 63;
    if (node >= nN) return;
    int half = lane >> 5, col = lane & 31;
    int beg = row_ptr[node], end = row_ptr[node + 1];
    f4 a[4][2];
#pragma unroll
    for (int u = 0; u < 4; u++) { a[u][0] = (f4){0,0,0,0}; a[u][1] = (f4){0,0,0,0}; }
    int e = beg;
    for (; e + 7 < end; e += 8) {
        int s[4];
#pragma unroll
        for (int u = 0; u < 4; u++) s[u] = csr_src[e + 2 * u + half];
        h8 v[4];
#pragma unroll
        for (int u = 0; u < 4; u++)
            v[u] = *(const h8*)(h + (size_t)s[u] * F + col * 8);
#pragma unroll
        for (int u = 0; u < 4; u++)
#pragma unroll
            for (int j = 0; j < 8; j++) a[u][j >> 2][j & 3] += (float)v[u][j];
    }
    for (int t = e + half; t < end; t += 2) {
        h8 v = *(const h8*)(h + (size_t)csr_src[t] * F + col * 8);
#pragma unroll
        for (int j = 0; j < 8; j++) a[0][j >> 2][j & 3] += (float)v[j];
    }
    float r[8];
#pragma unroll
    for (int j = 0; j < 8; j++)
        r[j] = (a[0][j >> 2][j & 3] + a[1][j >> 2][j & 3])
             + (a[2][j >> 2][j & 3] + a[3][j >> 2][j & 3]);
#pragma unroll
    for (int j = 0; j < 8; j++) r[j] += __shfl_xor(r[j], 32);
    if (half == 0) {
        h8 o;
#pragma unroll
        for (int j = 0; j < 8; j++) o[j] = (_Float16)r[j];
        *(h8*)(agg + (size_t)node * F + col * 8) = o;
    }
}

// ---------------- CSR aggregation, 64-wide: 8 lanes/edge, h8 loads + final epilogue ----------------
__global__ __launch_bounds__(256) void agg64h_k(
        const int* __restrict__ row_ptr, const int* __restrict__ csr_src,
        const _Float16* __restrict__ t3, const float* __restrict__ nin,
        const float* __restrict__ b2, float* __restrict__ out, int nN) {
    int node = (blockIdx.x * blockDim.x + threadIdx.x) >> 6;
    int lane = threadIdx.x & 63;
    if (node >= nN) return;
    int grp = lane >> 3, c = lane & 7;
    int beg = row_ptr[node], end = row_ptr[node + 1];
    float a0[8], a1[8];
#pragma unroll
    for (int j = 0; j < 8; j++) { a0[j] = 0.f; a1[j] = 0.f; }
    int e = beg;
    for (; e + 15 < end; e += 16) {
        int s0 = csr_src[e + grp], s1 = csr_src[e + 8 + grp];
        h8 v0 = *(const h8*)(t3 + (size_t)s0 * 64 + c * 8);
        h8 v1 = *(const h8*)(t3 + (size_t)s1 * 64 + c * 8);
#pragma unroll
        for (int j = 0; j < 8; j++) { a0[j] += (float)v0[j]; a1[j] += (float)v1[j]; }
    }
    for (int t = e + grp; t < end; t += 8) {
        h8 v = *(const h8*)(t3 + (size_t)csr_src[t] * 64 + c * 8);
#pragma unroll
        for (int j = 0; j < 8; j++) a0[j] += (float)v[j];
    }
    float r[8];
#pragma unroll
    for (int j = 0; j < 8; j++) {
        r[j] = a0[j] + a1[j];
        r[j] += __shfl_xor(r[j], 8);
        r[j] += __shfl_xor(r[j], 16);
        r[j] += __shfl_xor(r[j], 32);
    }
    if (grp == 0 && c < 5) {
        float ni = nin[node];
        float4 o;
        o.x = r[0] * ni + b2[c * 8 + 0];
        o.y = r[1] * ni + b2[c * 8 + 1];
        o.z = r[2] * ni + b2[c * 8 + 2];
        o.w = r[3] * ni + b2[c * 8 + 3];
        *(float4*)(out + (size_t)node * NCLS + c * 8) = o;
        o.x = r[4] * ni + b2[c * 8 + 4];
        o.y = r[5] * ni + b2[c * 8 + 5];
        o.z = r[6] * ni + b2[c * 8 + 6];
        o.w = r[7] * ni + b2[c * 8 + 7];
        *(float4*)(out + (size_t)node * NCLS + c * 8 + 4) = o;
    }
}

// ---------------- layer-0 GEMM: LDS-resident, 1024 thr, pre-swizzled Wt (linear stage) ----------------
__global__ __launch_bounds__(1024) void gemm0_k(
        const _Float16* __restrict__ A, const _Float16* __restrict__ Wt,
        _Float16* __restrict__ C, int M,
        const float* __restrict__ nin, const float* __restrict__ nout,
        const float* __restrict__ bias) {
    __shared__ _Float16 lds[256 * 256];      // 128 KiB
    char* ldsb = (char*)lds;
    const int tid  = threadIdx.x;
    const int lane = tid & 63;
    const int w    = tid >> 6;
    const int row0 = blockIdx.x * 256;

#pragma unroll
    for (int i = 0; i < 8; i++) {            // linear stage: content pre-swizzled
        int idx = (i * 1024 + tid) * 8;
        *(h8*)(ldsb + idx * 2) = *(const h8*)(Wt + idx);
    }

    int arow = row0 + w * 16 + (lane & 15);
    if (arow >= M) arow = M - 1;
    const _Float16* Ap = A + (size_t)arow * 256 + (lane >> 4) * 8;
    h8 areg[8];
#pragma unroll
    for (int i = 0; i < 8; i++) areg[i] = *(const h8*)(Ap + i * 32);

    __syncthreads();

    f4 acc[16];
#pragma unroll
    for (int n = 0; n < 16; n++) acc[n] = (f4){0.f, 0.f, 0.f, 0.f};

#pragma unroll
    for (int k0 = 0; k0 < 8; k0++) {
        int kb = (k0 * 32 + (lane >> 4) * 8) * 2;
#pragma unroll
        for (int n = 0; n < 16; n++) {
            int r    = n * 16 + (lane & 15);
            int byte = r * 512 + kb;
            h8 bf = *(const h8*)(ldsb + (byte ^ ((r & 7) << 4)));
            acc[n] = __builtin_amdgcn_mfma_f32_16x16x32_f16(areg[k0], bf, acc[n], 0, 0, 0);
        }
    }

    __syncthreads();

    const int g  = lane >> 4;
    const int rb = row0 + w * 16 + g * 4;
    float si[4], so[4];
#pragma unroll
    for (int r = 0; r < 4; r++) {
        int rr = rb + r; if (rr >= M) rr = M - 1;
        si[r] = nin[rr];
        so[r] = nout[rr];
    }
    char* warea = ldsb + w * 8192;
#pragma unroll
    for (int n = 0; n < 16; n++) {
        float bb = bias[n * 16 + (lane & 15)];
#pragma unroll
        for (int r = 0; r < 4; r++) {
            float x = fmaxf(acc[n][r] * si[r] + bb, 0.f) * so[r];
            int lrow = g * 4 + r;
            int lcol = n * 16 + (lane & 15);
            *(_Float16*)(warea + (size_t)(lrow * 256 + lcol) * 2) = (_Float16)x;
        }
    }

    _Float16* Crow = C + (size_t)(row0 + w * 16) * 256;
#pragma unroll
    for (int i = 0; i < 8; i++) {
        int off  = i * 1024 + lane * 16;
        int lrow = off >> 9;
        int grow = row0 + w * 16 + lrow;
        h8 v = *(const h8*)(warea + off);
        if (grow < M) *(h8*)((char*)Crow + off) = v;
    }
}

// ---------------- FUSED layer-1 GEMM + layer-2 GEMM: hA @ W1 -> (epi) -> @ W2 -> t3 ----------------
// h1 never touches HBM: epilogue writes each wave's 16x256 h1 rows to its private
// swizzled LDS area, re-fragments as A-operands, stages Wt2 into freed LDS, emits t3.
__global__ __launch_bounds__(1024) void gemm12_k(
        const _Float16* __restrict__ A, const _Float16* __restrict__ Wt1s,
        const _Float16* __restrict__ Wt2s, _Float16* __restrict__ t3, int M,
        const float* __restrict__ nin, const float* __restrict__ nout,
        const float* __restrict__ bias) {
    __shared__ _Float16 lds[256 * 256];      // 128 KiB
    char* ldsb = (char*)lds;
    const int tid  = threadIdx.x;
    const int lane = tid & 63;
    const int w    = tid >> 6;
    const int row0 = blockIdx.x * 256;

    // ---- stage Wt1 (128 KB, linear; content pre-swizzled) ----
#pragma unroll
    for (int i = 0; i < 8; i++) {
        int idx = (i * 1024 + tid) * 8;
        *(h8*)(ldsb + idx * 2) = *(const h8*)(Wt1s + idx);
    }

    int arow = row0 + w * 16 + (lane & 15);
    if (arow >= M) arow = M - 1;
    const _Float16* Ap = A + (size_t)arow * 256 + (lane >> 4) * 8;
    h8 areg[8];
#pragma unroll
    for (int i = 0; i < 8; i++) areg[i] = *(const h8*)(Ap + i * 32);

    __syncthreads();

    // ---- k-loop 1: h1 accumulators ----
    f4 acc[16];
#pragma unroll
    for (int n = 0; n < 16; n++) acc[n] = (f4){0.f, 0.f, 0.f, 0.f};
#pragma unroll
    for (int k0 = 0; k0 < 8; k0++) {
        int kb = (k0 * 32 + (lane >> 4) * 8) * 2;
#pragma unroll
        for (int n = 0; n < 16; n++) {
            int r    = n * 16 + (lane & 15);
            int byte = r * 512 + kb;
            h8 bf = *(const h8*)(ldsb + (byte ^ ((r & 7) << 4)));
            acc[n] = __builtin_amdgcn_mfma_f32_16x16x32_f16(areg[k0], bf, acc[n], 0, 0, 0);
        }
    }

    __syncthreads();   // all waves done reading Wt1

    // ---- epilogue 1 -> wave-private swizzled warea (h1 tile, fp16) ----
    const int g  = lane >> 4;
    const int rb = row0 + w * 16 + g * 4;
    float si[4], so[4];
#pragma unroll
    for (int r = 0; r < 4; r++) {
        int rr = rb + r; if (rr >= M) rr = M - 1;
        si[r] = nin[rr];
        so[r] = nout[rr];
    }
    char* warea = ldsb + w * 8192;
#pragma unroll
    for (int n = 0; n < 16; n++) {
        float bb = bias[n * 16 + (lane & 15)];
#pragma unroll
        for (int r = 0; r < 4; r++) {
            float x = fmaxf(acc[n][r] * si[r] + bb, 0.f) * so[r];
            int lrow = g * 4 + r;
            int lcol = n * 16 + (lane & 15);
            int byte = lrow * 512 + lcol * 2;
            *(_Float16*)(warea + (byte ^ ((lrow & 7) << 4))) = (_Float16)x;
        }
    }

    // ---- re-fragment h1 as A-operands (wave-local; compiler inserts lgkmcnt) ----
    h8 areg2[8];
    {
        int lr = lane & 15;
#pragma unroll
        for (int k0 = 0; k0 < 8; k0++) {
            int byte = lr * 512 + k0 * 64 + (lane >> 4) * 16;
            areg2[k0] = *(const h8*)(warea + (byte ^ ((lr & 7) << 4)));
        }
    }
    __syncthreads();   // everyone consumed own warea; low 32KB free for Wt2

    // ---- stage Wt2 (32 KB, linear; pre-swizzled) ----
#pragma unroll
    for (int i = 0; i < 2; i++) {
        int idx = (i * 1024 + tid) * 8;
        *(h8*)(ldsb + idx * 2) = *(const h8*)(Wt2s + idx);
    }
    __syncthreads();

    // ---- k-loop 2: t3 = h1 @ Wt2^T (64 cols) ----
    f4 acc2[4];
#pragma unroll
    for (int n = 0; n < 4; n++) acc2[n] = (f4){0.f, 0.f, 0.f, 0.f};
#pragma unroll
    for (int k0 = 0; k0 < 8; k0++) {
        int kb = k0 * 64 + (lane >> 4) * 16;
#pragma unroll
        for (int n = 0; n < 4; n++) {
            int r    = n * 16 + (lane & 15);
            int byte = r * 512 + kb;
            h8 bf = *(const h8*)(ldsb + (byte ^ ((r & 7) << 4)));
            acc2[n] = __builtin_amdgcn_mfma_f32_16x16x32_f16(areg2[k0], bf, acc2[n], 0, 0, 0);
        }
    }

    // ---- t3 tile via wave-private area at 32KB+ (no overlap with Wt2 region) ----
    char* tarea = ldsb + 32768 + w * 2048;   // 16 rows x 128 B
#pragma unroll
    for (int n = 0; n < 4; n++)
#pragma unroll
        for (int r = 0; r < 4; r++) {
            int lrow = g * 4 + r;
            int c = n * 16 + (lane & 15);
            *(_Float16*)(tarea + lrow * 128 + c * 2) = (_Float16)acc2[n][r];
        }
#pragma unroll
    for (int i = 0; i < 2; i++) {            // coalesced 16B stores, 2KB/wave
        int off  = i * 1024 + lane * 16;
        int lrow = off >> 7;
        int grow = row0 + w * 16 + lrow;
        h8 v = *(const h8*)(tarea + off);
        if (grow < M) *(h8*)((char*)t3 + (size_t)grow * 128 + (off & 127)) = v;
    }
}

extern "C" void kernel_launch(void* const* d_in, const int* in_sizes, int n_in,
                              void* d_out, int out_size, void* d_ws, size_t ws_size,
                              hipStream_t stream) {
    const float* features = (const float*)d_in[0];
    const int*   src      = (const int*)d_in[1];
    const int*   dst      = (const int*)d_in[2];
    const float* W0       = (const float*)d_in[3];
    const float* b0       = (const float*)d_in[4];
    const float* W1       = (const float*)d_in[5];
    const float* b1       = (const float*)d_in[6];
    const float* W2       = (const float*)d_in[7];
    const float* b2       = (const float*)d_in[8];
    float* out = (float*)d_out;

    // ---- workspace carve (16B-aligned sections) ----
    char* ws = (char*)d_ws;
    const size_t H_BYTES = (size_t)NN * F * 2;             // 51.2 MB
    _Float16* hA   = (_Float16*)(ws);
    _Float16* hB   = (_Float16*)(ws + H_BYTES);
    _Float16* t3h  = (_Float16*)(ws + 2 * H_BYTES);        // [NN,64] fp16
    char* q = ws + 2 * H_BYTES + (size_t)NN * 64 * 2;
    int* csr_src    = (int*)q;               q += (size_t)NE * 4;             // 12.8 MB
    unsigned* ebuf  = (unsigned*)q;          q += (size_t)NE * 4;             // 12.8 MB
    unsigned* pcnt  = (unsigned*)q;          q += (size_t)NBLK_H * CW * 4;    // 25.6 MB
    unsigned* pl    = (unsigned*)q;          q += (size_t)8 * CW * 4;         // 800 KB
    unsigned* ph    = (unsigned*)q;          q += (size_t)8 * CW * 4;         // 800 KB
    unsigned* pcc   = (unsigned*)q;          q += (size_t)NBLK_H * NC * 4 + 1024;
    unsigned* curoff= (unsigned*)q;          q += (size_t)NBLK_H * NC * 4 + 1024;
    char* p = q;
    const size_t SB = 401408;
    unsigned* totals = (unsigned*)(p + 0 * SB);
    int*   cbase   = (int*)(p + 1 * SB);
    int*   row_ptr = (int*)(p + 2 * SB);
    float* nout    = (float*)(p + 3 * SB);
    float* nin     = (float*)(p + 4 * SB);
    _Float16* Wt0  = (_Float16*)(p + 5 * SB);              // 128 KB (pre-swizzled)
    _Float16* Wt1  = (_Float16*)(p + 5 * SB + 131072);
    _Float16* Wt2  = (_Float16*)(p + 5 * SB + 262144);     // 32 KB

    const int AGG_BLOCKS = (NN * 64 + 255) / 256;
    const int GB = (NN + 255) / 256;                       // 391 gemm blocks

    // ---- CSR build: LDS histograms -> offset scans -> 2-pass radix (no memsets) ----
    hist_k<<<NBLK_H, 512, 0, stream>>>(src, dst, pcnt, pcc);
    {
        dim3 rg((CW + 255) / 256, 8);
        redA_k<<<rg, 256, 0, stream>>>(pcnt, pl, ph);
    }
    nout2_k<<<(CW + 255) / 256, 256, 0, stream>>>(pl, ph, nout);
    offsets_k<<<NC, 256, 0, stream>>>(pcc, curoff, totals);
    base_k<<<1, 512, 0, stream>>>(totals, cbase);
    p1scat_k<<<NBLK_H, 512, 0, stream>>>(src, dst, cbase, curoff, ebuf);
    p2build_k<<<NC, 512, 0, stream>>>(cbase, ebuf, csr_src, row_ptr, nin);

    // ---- fused one-time conversions ----
    {
        int total = NN * 64 + 147456;
        conv_fused_k<<<(total + 255) / 256, 256, 0, stream>>>(
            (const float4*)features, nout, (h4*)hB, W0, W1, W2, Wt0, Wt1, Wt2);
    }

    // ---- layer 0: agg -> gemm ----
    agg256h_k<<<AGG_BLOCKS, 256, 0, stream>>>(row_ptr, csr_src, hB, hA, NN);
    gemm0_k<<<GB, 1024, 0, stream>>>(hA, Wt0, hB, NN, nin, nout, b0);

    // ---- layer 1 agg; then fused L1-gemm + L2-gemm (h1 never hits HBM) ----
    agg256h_k<<<AGG_BLOCKS, 256, 0, stream>>>(row_ptr, csr_src, hB, hA, NN);
    gemm12_k<<<GB, 1024, 0, stream>>>(hA, Wt1, Wt2, t3h, NN, nin, nout, b1);

    // ---- final aggregation + epilogue ----
    agg64h_k<<<AGG_BLOCKS, 256, 0, stream>>>(row_ptr, csr_src, t3h, nin, b2, out, NN);
}